// Round 24
// baseline (180.414 us; speedup 1.0000x reference)
//
#include <hip/hip_runtime.h>
#include <hip/hip_bf16.h>

#define BATCH   32768
#define DIM     2048
#define NHEADS  28
#define NCOLS   280
#define LOSS_SCALE (1.0f / (float)(BATCH * NHEADS))

typedef __attribute__((ext_vector_type(8))) short short8;
typedef __attribute__((ext_vector_type(4))) short s4vec;
typedef __attribute__((ext_vector_type(4))) float f32x4;

__device__ __forceinline__ short f2bf(float f) {
    union { __hip_bfloat16 h; short s; } u; u.h = __float2bfloat16(f); return u.s;
}

// ---------------------------------------------------------------------------
// W pre-swizzle (R8-proven): W [280][2048] f32 -> Wswz bf16, 16x16x32 B-frag
// order: short idx = (nt*64 + kt)*512 + lane*8 + j
//   n = nt*16 + (lane&15), d = kt*32 + (lane>>4)*8 + j
// ---------------------------------------------------------------------------
__global__ void mvh_swz(const float* __restrict__ W, short* __restrict__ Wswz) {
    int t = blockIdx.x * 256 + threadIdx.x;      // 73728 threads
    int lane = t & 63;
    int ks = (t >> 6) & 63;
    int nt = t >> 12;                            // 0..17
    int n = nt * 16 + (lane & 15);
    int d = ks * 32 + (lane >> 4) * 8;
    short8 v;
    #pragma unroll
    for (int j = 0; j < 8; j++) v[j] = 0;
    if (n < NCOLS) {
        const float* src = W + (size_t)n * DIM + d;
        #pragma unroll
        for (int j = 0; j < 8; j++) v[j] = f2bf(src[j]);
    }
    *(short8*)(Wswz + (size_t)t * 8) = v;
}

// ---------------------------------------------------------------------------
// DIAGNOSTIC build: R22 (best, 97.9 µs) run TWICE per dispatch (pass 0 ->
// d_ws scratch, pass 1 -> real out) so mvh_gemm's duration (~190 µs)
// exceeds the harness poison-fills (~150 µs) and its counters finally
// surface in the top-5. Work per pass is byte-identical to R22.
// ---------------------------------------------------------------------------
#define B_TILE 18432
#define AB(b)  ((b) * 8192)
#define BB(b)  (16384 + (b) * B_TILE)
#define CL_PITCH 292

#define SB0() __builtin_amdgcn_sched_barrier(0)
#define WAITV(N) asm volatile("s_waitcnt vmcnt(" #N ") lgkmcnt(0)" ::: "memory")
#define BARN(N) do { SB0(); WAITV(N); __builtin_amdgcn_s_barrier(); SB0(); } while (0)

__global__ __launch_bounds__(512, 4)
void mvh_gemm(const float* __restrict__ hidden, const short* __restrict__ Wswz,
              const float* __restrict__ bias, float* __restrict__ logits,
              const int* __restrict__ labels, float* __restrict__ loss_out,
              float* __restrict__ logits_s, float* __restrict__ loss_s) {
    __shared__ __align__(16) char lds[53248];

    const int tid  = threadIdx.x;
    const int lane = tid & 63;
    const int wave = tid >> 6;
    const int kph   = wave >> 2;        // tile-parity owner
    const int wsub  = (wave >> 1) & 1;  // 32-row slice
    const int nhalf = wave & 1;         // 144-col half
    const int l15 = lane & 15, lhi = lane >> 4;
    // T1: bijective XCD swizzle (nwg=512, 512%8==0)
    const int swzblk = (blockIdx.x & 7) * 64 + (blockIdx.x >> 3);
    const int rowbase = swzblk * 64;

    const int ar  = tid >> 3;
    const int ak4 = (tid & 7) * 4;
    const float* gAbase = hidden + (size_t)(rowbase + ar) * DIM + ak4;
    const int awbyte = (ar >> 4) * 1024 + ((ar & 15) + 16 * (ak4 >> 3)) * 16 + (ak4 & 4) * 2;

    f32x4 acc0[9], acc1[9];
    f32x4 ga0, ga1;   // one A-group (2 tiles) in flight

#define LOADA2(grp) do { \
    const float* p_ = gAbase + (size_t)(grp) * 64; \
    ga0 = *(const f32x4*)(p_); \
    ga1 = *(const f32x4*)(p_ + 32); \
    SB0(); \
} while (0)

#define WRA1(dstoff, slot, src) do { \
    s4vec w_; \
    w_[0] = f2bf(src[0]); w_[1] = f2bf(src[1]); w_[2] = f2bf(src[2]); w_[3] = f2bf(src[3]); \
    *(s4vec*)(lds + (dstoff) + (slot) * 4096 + awbyte) = w_; \
} while (0)

#define WRITEA2(dstoff) do { WRA1(dstoff, 0, ga0); WRA1(dstoff, 1, ga1); } while (0)

#define STAGE_B(dstoff, kt) do { \
    _Pragma("unroll") \
    for (int i_ = 0; i_ < 3; i_++) { \
        if (i_ < 2 || tid < 128) { \
            int g_ = (i_ < 2) ? (i_ * 512 + tid) : (1024 + tid); \
            const short* gp_ = Wswz + (size_t)((g_ >> 6) * 64 + (kt)) * 512 + (g_ & 63) * 8; \
            __builtin_amdgcn_global_load_lds((const __attribute__((address_space(1))) void*)gp_, \
                (__attribute__((address_space(3))) void*)(lds + (dstoff) + g_ * 16), 16, 0, 0); \
        } \
    } \
    SB0(); \
} while (0)

#define COMPUTE(aoff, boff) do { \
    short8 af0_ = *(const short8*)(lds + (aoff) + (wsub * 2 + 0) * 1024 + lane * 16); \
    short8 af1_ = *(const short8*)(lds + (aoff) + (wsub * 2 + 1) * 1024 + lane * 16); \
    __builtin_amdgcn_s_setprio(1); \
    _Pragma("unroll") \
    for (int n_ = 0; n_ < 9; n_++) { \
        short8 bf_ = *(const short8*)(lds + (boff) + (nhalf * 9 + n_) * 1024 + lane * 16); \
        acc0[n_] = __builtin_amdgcn_mfma_f32_16x16x32_bf16(af0_, bf_, acc0[n_], 0, 0, 0); \
        acc1[n_] = __builtin_amdgcn_mfma_f32_16x16x32_bf16(af1_, bf_, acc1[n_], 0, 0, 0); \
    } \
    __builtin_amdgcn_s_setprio(0); \
} while (0)

    #pragma unroll 1
    for (int pass = 0; pass < 2; pass++) {
        float* Lg = pass ? logits : logits_s;
        float* Lo = pass ? loss_out : loss_s;

        #pragma unroll
        for (int n = 0; n < 9; n++) { acc0[n] = (f32x4)0.0f; acc1[n] = (f32x4)0.0f; }

        // ---- prologue: group 0 -> Abuf0; B(0) -> B0; group 1 -> regs ----
        LOADA2(0);
        WRITEA2(AB(0));
        STAGE_B(BB(0), 0);
        LOADA2(1);
        BARN(2);                 // drain B(0); A(group1) stays in flight

        // ---- main loop: 32 groups x 2 tiles (R17/R22 byte-exact) ----
        #pragma unroll 1
        for (int g = 0; g < 32; g++) {
            const int t0 = g * 2;
            const int ac = AB(g & 1);
            const int an = AB((g & 1) ^ 1);
            if (g < 31) WRITEA2(an);
            STAGE_B(BB(1), t0 + 1);
            if (kph == 0) COMPUTE(ac, BB(0));
            BARN(0);
            if (g < 31) STAGE_B(BB(0), t0 + 2);
            if (g < 30) LOADA2(g + 2);
            if (kph == 1) COMPUTE(ac + 4096, BB(1));
            if (g < 30) { BARN(2); } else { BARN(0); }
        }

        // ---- fused epilogue v2: Cl[32][292], bias on read ----
        float* Cl  = (float*)lds;
        float* red = (float*)(lds + 38912);
        float lsum = 0.0f;

        #pragma unroll 1
        for (int s = 0; s < 2; s++) {
            __syncthreads();
            if (kph == 1 && wsub == s) {
                #pragma unroll
                for (int nf = 0; nf < 9; nf++) {
                    int c = nhalf * 144 + nf * 16 + l15;
                    #pragma unroll
                    for (int r = 0; r < 4; r++) {
                        Cl[(lhi * 4 + r) * CL_PITCH + c]      = acc0[nf][r];
                        Cl[(16 + lhi * 4 + r) * CL_PITCH + c] = acc1[nf][r];
                    }
                }
            }
            __syncthreads();
            if (kph == 0 && wsub == s) {
                #pragma unroll
                for (int nf = 0; nf < 9; nf++) {
                    int c = nhalf * 144 + nf * 16 + l15;
                    #pragma unroll
                    for (int r = 0; r < 4; r++) {
                        Cl[(lhi * 4 + r) * CL_PITCH + c]      += acc0[nf][r];
                        Cl[(16 + lhi * 4 + r) * CL_PITCH + c] += acc1[nf][r];
                    }
                }
            }
            __syncthreads();
            #pragma unroll 1
            for (int i = tid; i < 32 * 70; i += 512) {
                int lr = i / 70, ch = i - lr * 70;
                f32x4 v  = *(const f32x4*)(Cl + lr * CL_PITCH + ch * 4);
                f32x4 bv = *(const f32x4*)(bias + ch * 4);
                *(f32x4*)(Lg + (size_t)(rowbase + s * 32 + lr) * NCOLS + ch * 4) = v + bv;
            }
            #pragma unroll 1
            for (int p = tid; p < 32 * NHEADS; p += 512) {
                int lr = p / NHEADS, h = p - lr * NHEADS;
                const float* x  = Cl + lr * CL_PITCH + h * 10;
                const float* bb = bias + h * 10;
                float xv[10];
                #pragma unroll
                for (int j = 0; j < 10; j++) xv[j] = x[j] + bb[j];
                float mx = xv[0];
                #pragma unroll
                for (int j = 1; j < 10; j++) mx = fmaxf(mx, xv[j]);
                float sm = 0.0f;
                #pragma unroll
                for (int j = 0; j < 10; j++) sm += __expf(xv[j] - mx);
                int lab = labels[(size_t)(rowbase + s * 32 + lr) * NHEADS + h];
                float xl = xv[0];
                #pragma unroll
                for (int j = 1; j < 10; j++) xl = (lab == j) ? xv[j] : xl;
                lsum += mx + __logf(sm) - xl;
            }
        }

        #pragma unroll
        for (int off = 32; off > 0; off >>= 1)
            lsum += __shfl_down(lsum, off, 64);
        if (lane == 0) red[wave] = lsum;
        __syncthreads();
        if (tid == 0) {
            float t = red[0] + red[1] + red[2] + red[3]
                    + red[4] + red[5] + red[6] + red[7];
            atomicAdd(Lo, t * LOSS_SCALE);
        }
        __syncthreads();   // red[] read complete before next pass clobbers LDS
    }

#undef LOADA2
#undef WRA1
#undef WRITEA2
#undef STAGE_B
#undef COMPUTE
}

extern "C" void kernel_launch(void* const* d_in, const int* in_sizes, int n_in,
                              void* d_out, int out_size, void* d_ws, size_t ws_size,
                              hipStream_t stream) {
    const float* hidden = (const float*)d_in[0];
    const int* labels   = (const int*)d_in[1];
    const float* W      = (const float*)d_in[2];
    const float* bias   = (const float*)d_in[3];
    float* out = (float*)d_out;
    short* Wswz = (short*)d_ws;                                 // 1.18 MB
    float* loss_s   = (float*)((char*)d_ws + (32u << 20));      // scratch loss
    float* logits_s = (float*)((char*)d_ws + (64u << 20));      // 36.7 MB scratch

    (void)hipMemsetAsync(d_out, 0, sizeof(float), stream);     // zero loss accumulator
    mvh_swz<<<288, 256, 0, stream>>>(W, Wswz);
    mvh_gemm<<<512, 512, 0, stream>>>(hidden, Wswz, bias, out + 1, labels, out,
                                      logits_s, loss_s);
}

// Round 25
// 97.278 us; speedup vs baseline: 1.8546x; 1.8546x over previous
//
#include <hip/hip_runtime.h>
#include <hip/hip_bf16.h>

#define BATCH   32768
#define DIM     2048
#define NHEADS  28
#define NCOLS   280
#define LOSS_SCALE (1.0f / (float)(BATCH * NHEADS))

typedef __attribute__((ext_vector_type(8))) short short8;
typedef __attribute__((ext_vector_type(4))) short s4vec;
typedef __attribute__((ext_vector_type(4))) float f32x4;

__device__ __forceinline__ short f2bf(float f) {
    union { __hip_bfloat16 h; short s; } u; u.h = __float2bfloat16(f); return u.s;
}

// ---------------------------------------------------------------------------
// W pre-swizzle (R8-proven): W [280][2048] f32 -> Wswz bf16, 16x16x32 B-frag
// order: short idx = (nt*64 + kt)*512 + lane*8 + j
//   n = nt*16 + (lane&15), d = kt*32 + (lane>>4)*8 + j
// ---------------------------------------------------------------------------
__global__ void mvh_swz(const float* __restrict__ W, short* __restrict__ Wswz) {
    int t = blockIdx.x * 256 + threadIdx.x;      // 73728 threads
    int lane = t & 63;
    int ks = (t >> 6) & 63;
    int nt = t >> 12;                            // 0..17
    int n = nt * 16 + (lane & 15);
    int d = ks * 32 + (lane >> 4) * 8;
    short8 v;
    #pragma unroll
    for (int j = 0; j < 8; j++) v[j] = 0;
    if (n < NCOLS) {
        const float* src = W + (size_t)n * DIM + d;
        #pragma unroll
        for (int j = 0; j < 8; j++) v[j] = f2bf(src[j]);
    }
    *(short8*)(Wswz + (size_t)t * 8) = v;
}

// ---------------------------------------------------------------------------
// FINAL: GEMM + FUSED LOSS (R22, best verified: 97.9 µs total).
// R24 measurement (2x-pass diagnostic): MfmaUtil 14%, VALUBusy 12%, HBM 16%,
// conflicts ~2cy/LDS-instr, occupancy 45% -> latency/sync-bound plateau;
// invariant under all 24 rounds of schedule/buffer/barrier/pattern search.
// Structure: grid 512 x 512 thr (8 waves: kph parity x wsub x nhalf),
// BM=64, BK=32, 32 groups of 2 tiles; LDS 53248 (2 blocks/CU); counted
// vmcnt raw barriers (A-group flight ~1 interval, B dbuf DMA); T5 setprio
// around MFMA cluster; T1 bijective XCD blockIdx swizzle; fused epilogue
// (Cl[32][292] merge, bias-on-read, contiguous stores, per-block logsumexp
// + one atomicAdd) - no separate loss dispatch.
// ---------------------------------------------------------------------------
#define B_TILE 18432
#define AB(b)  ((b) * 8192)
#define BB(b)  (16384 + (b) * B_TILE)
#define CL_PITCH 292

#define SB0() __builtin_amdgcn_sched_barrier(0)
#define WAITV(N) asm volatile("s_waitcnt vmcnt(" #N ") lgkmcnt(0)" ::: "memory")
#define BARN(N) do { SB0(); WAITV(N); __builtin_amdgcn_s_barrier(); SB0(); } while (0)

__global__ __launch_bounds__(512, 4)
void mvh_gemm(const float* __restrict__ hidden, const short* __restrict__ Wswz,
              const float* __restrict__ bias, float* __restrict__ logits,
              const int* __restrict__ labels, float* __restrict__ loss_out) {
    __shared__ __align__(16) char lds[53248];

    const int tid  = threadIdx.x;
    const int lane = tid & 63;
    const int wave = tid >> 6;
    const int kph   = wave >> 2;        // tile-parity owner
    const int wsub  = (wave >> 1) & 1;  // 32-row slice
    const int nhalf = wave & 1;         // 144-col half
    const int l15 = lane & 15, lhi = lane >> 4;
    // T1: bijective XCD swizzle (nwg=512, 512%8==0): xcd = bid&7 gets
    // 64 consecutive row-blocks -> contiguous 4096-row A span per XCD.
    const int swzblk = (blockIdx.x & 7) * 64 + (blockIdx.x >> 3);
    const int rowbase = swzblk * 64;

    // A staging map (R8-proven): row ar=tid>>3, k-floats [ak4, ak4+4).
    const int ar  = tid >> 3;
    const int ak4 = (tid & 7) * 4;
    const float* gAbase = hidden + (size_t)(rowbase + ar) * DIM + ak4;
    const int awbyte = (ar >> 4) * 1024 + ((ar & 15) + 16 * (ak4 >> 3)) * 16 + (ak4 & 4) * 2;

    f32x4 acc0[9], acc1[9];
    #pragma unroll
    for (int n = 0; n < 9; n++) { acc0[n] = (f32x4)0.0f; acc1[n] = (f32x4)0.0f; }

    f32x4 ga0, ga1;   // one A-group (2 tiles) in flight

#define LOADA2(grp) do { \
    const float* p_ = gAbase + (size_t)(grp) * 64; \
    ga0 = *(const f32x4*)(p_); \
    ga1 = *(const f32x4*)(p_ + 32); \
    SB0(); \
} while (0)

#define WRA1(dstoff, slot, src) do { \
    s4vec w_; \
    w_[0] = f2bf(src[0]); w_[1] = f2bf(src[1]); w_[2] = f2bf(src[2]); w_[3] = f2bf(src[3]); \
    *(s4vec*)(lds + (dstoff) + (slot) * 4096 + awbyte) = w_; \
} while (0)

#define WRITEA2(dstoff) do { WRA1(dstoff, 0, ga0); WRA1(dstoff, 1, ga1); } while (0)

#define STAGE_B(dstoff, kt) do { \
    _Pragma("unroll") \
    for (int i_ = 0; i_ < 3; i_++) { \
        if (i_ < 2 || tid < 128) { \
            int g_ = (i_ < 2) ? (i_ * 512 + tid) : (1024 + tid); \
            const short* gp_ = Wswz + (size_t)((g_ >> 6) * 64 + (kt)) * 512 + (g_ & 63) * 8; \
            __builtin_amdgcn_global_load_lds((const __attribute__((address_space(1))) void*)gp_, \
                (__attribute__((address_space(3))) void*)(lds + (dstoff) + g_ * 16), 16, 0, 0); \
        } \
    } \
    SB0(); \
} while (0)

// T5: setprio(1) around the MFMA cluster (kph role-split regime).
#define COMPUTE(aoff, boff) do { \
    short8 af0_ = *(const short8*)(lds + (aoff) + (wsub * 2 + 0) * 1024 + lane * 16); \
    short8 af1_ = *(const short8*)(lds + (aoff) + (wsub * 2 + 1) * 1024 + lane * 16); \
    __builtin_amdgcn_s_setprio(1); \
    _Pragma("unroll") \
    for (int n_ = 0; n_ < 9; n_++) { \
        short8 bf_ = *(const short8*)(lds + (boff) + (nhalf * 9 + n_) * 1024 + lane * 16); \
        acc0[n_] = __builtin_amdgcn_mfma_f32_16x16x32_bf16(af0_, bf_, acc0[n_], 0, 0, 0); \
        acc1[n_] = __builtin_amdgcn_mfma_f32_16x16x32_bf16(af1_, bf_, acc1[n_], 0, 0, 0); \
    } \
    __builtin_amdgcn_s_setprio(0); \
} while (0)

    // ---- prologue: group 0 -> Abuf0; B(0) -> B0; group 1 -> regs ----
    LOADA2(0);
    WRITEA2(AB(0));
    STAGE_B(BB(0), 0);
    LOADA2(1);
    BARN(2);                 // drain B(0); A(group1) stays in flight

    // ---- main loop: 32 groups x 2 tiles (R17 byte-exact) ----
    #pragma unroll 1
    for (int g = 0; g < 32; g++) {
        const int t0 = g * 2;
        const int ac = AB(g & 1);
        const int an = AB((g & 1) ^ 1);
        // sub0: tile t0 (even, B0). Publish A(group g+1); stage B(t0+1).
        if (g < 31) WRITEA2(an);
        STAGE_B(BB(1), t0 + 1);
        if (kph == 0) COMPUTE(ac, BB(0));
        BARN(0);
        // sub1: tile t0+1 (odd, B1). Stage B(t0+2) BEFORE issuing A(g+2).
        if (g < 31) STAGE_B(BB(0), t0 + 2);
        if (g < 30) LOADA2(g + 2);
        if (kph == 1) COMPUTE(ac + 4096, BB(1));
        if (g < 30) { BARN(2); } else { BARN(0); }
    }

#undef LOADA2
#undef WRA1
#undef WRITEA2
#undef STAGE_B
#undef COMPUTE

    // ---- fused epilogue v2 (R16-proven): Cl[32][292], bias on read ----
    float* Cl  = (float*)lds;                       // 37376 B
    float* red = (float*)(lds + 38912);
    float lsum = 0.0f;

    #pragma unroll 1
    for (int s = 0; s < 2; s++) {
        __syncthreads();
        if (kph == 1 && wsub == s) {
            #pragma unroll
            for (int nf = 0; nf < 9; nf++) {
                int c = nhalf * 144 + nf * 16 + l15;
                #pragma unroll
                for (int r = 0; r < 4; r++) {
                    Cl[(lhi * 4 + r) * CL_PITCH + c]      = acc0[nf][r];
                    Cl[(16 + lhi * 4 + r) * CL_PITCH + c] = acc1[nf][r];
                }
            }
        }
        __syncthreads();
        if (kph == 0 && wsub == s) {
            #pragma unroll
            for (int nf = 0; nf < 9; nf++) {
                int c = nhalf * 144 + nf * 16 + l15;
                #pragma unroll
                for (int r = 0; r < 4; r++) {
                    Cl[(lhi * 4 + r) * CL_PITCH + c]      += acc0[nf][r];
                    Cl[(16 + lhi * 4 + r) * CL_PITCH + c] += acc1[nf][r];
                }
            }
        }
        __syncthreads();
        #pragma unroll 1
        for (int i = tid; i < 32 * 70; i += 512) {
            int lr = i / 70, ch = i - lr * 70;
            f32x4 v  = *(const f32x4*)(Cl + lr * CL_PITCH + ch * 4);
            f32x4 bv = *(const f32x4*)(bias + ch * 4);
            *(f32x4*)(logits + (size_t)(rowbase + s * 32 + lr) * NCOLS + ch * 4) = v + bv;
        }
        #pragma unroll 1
        for (int p = tid; p < 32 * NHEADS; p += 512) {
            int lr = p / NHEADS, h = p - lr * NHEADS;
            const float* x  = Cl + lr * CL_PITCH + h * 10;
            const float* bb = bias + h * 10;
            float xv[10];
            #pragma unroll
            for (int j = 0; j < 10; j++) xv[j] = x[j] + bb[j];
            float mx = xv[0];
            #pragma unroll
            for (int j = 1; j < 10; j++) mx = fmaxf(mx, xv[j]);
            float sm = 0.0f;
            #pragma unroll
            for (int j = 0; j < 10; j++) sm += __expf(xv[j] - mx);
            int lab = labels[(size_t)(rowbase + s * 32 + lr) * NHEADS + h];
            float xl = xv[0];
            #pragma unroll
            for (int j = 1; j < 10; j++) xl = (lab == j) ? xv[j] : xl;
            lsum += mx + __logf(sm) - xl;
        }
    }

    #pragma unroll
    for (int off = 32; off > 0; off >>= 1)
        lsum += __shfl_down(lsum, off, 64);
    if (lane == 0) red[wave] = lsum;
    __syncthreads();
    if (tid == 0) {
        float t = red[0] + red[1] + red[2] + red[3]
                + red[4] + red[5] + red[6] + red[7];
        atomicAdd(loss_out, t * LOSS_SCALE);
    }
}

extern "C" void kernel_launch(void* const* d_in, const int* in_sizes, int n_in,
                              void* d_out, int out_size, void* d_ws, size_t ws_size,
                              hipStream_t stream) {
    const float* hidden = (const float*)d_in[0];
    const int* labels   = (const int*)d_in[1];
    const float* W      = (const float*)d_in[2];
    const float* bias   = (const float*)d_in[3];
    float* out = (float*)d_out;
    short* Wswz = (short*)d_ws;   // 589824 bf16 = 1.18 MB

    (void)hipMemsetAsync(d_out, 0, sizeof(float), stream);     // zero loss accumulator
    mvh_swz<<<288, 256, 0, stream>>>(W, Wswz);
    mvh_gemm<<<512, 512, 0, stream>>>(hidden, Wswz, bias, out + 1, labels, out);
}